// Round 7
// baseline (186.879 us; speedup 1.0000x reference)
//
#include <hip/hip_runtime.h>
#include <math.h>

#define K_CODES 512
#define DIM 64
#define NPTS (32 * 4096)   // 131072 points (B*HW)
#define NQ (NPTS * DIM)    // 8388608 quant_out elements
#define KSPLIT 4
#define KRANGE (K_CODES / KSPLIT) // 128 codes per wave
#define PPB 64             // points per block (one per lane)

// d_out layout (floats): [quant_out: 8388608][loss: 1][indices-as-float: 131072]

__global__ void init_kernel(float* __restrict__ loss) { loss[0] = 0.0f; }

// Block: 256 threads = 4 waves. Wave w scans codes [w*128, w*128+128) for the
// block's 64 points (point = lane). x held in 16 NAMED float4s (forced into
// VGPRs); launch_bounds(256,2) lifts the VGPR cap to 256 so they stay there.
__global__ __launch_bounds__(256, 2) void vq_kernel(const float* __restrict__ qin,
                                                    const float* __restrict__ cb,
                                                    float* __restrict__ out,
                                                    float* __restrict__ loss_acc,
                                                    float* __restrict__ idx_out) {
    __shared__ float shalf[K_CODES];
    __shared__ float sscore[KSPLIT][PPB];
    __shared__ int   sidx[KSPLIT][PPB];
    __shared__ int   sfinal[PPB];
    __shared__ float wsum[4];

    int tid = threadIdx.x;
    int lane = tid & 63;
    int w = tid >> 6;

    // cooperative 0.5*||e_k||^2 table (2 rounds of 256 codes)
    for (int kk = 0; kk < K_CODES; kk += 256) {
        int k = kk + tid;
        const float4* c4 = (const float4*)(cb + k * DIM);
        float s0 = 0.f, s1 = 0.f, s2 = 0.f, s3 = 0.f;
#pragma unroll
        for (int i = 0; i < DIM / 4; ++i) {
            float4 c = c4[i];
            s0 = fmaf(c.x, c.x, s0); s1 = fmaf(c.y, c.y, s1);
            s2 = fmaf(c.z, c.z, s2); s3 = fmaf(c.w, c.w, s3);
        }
        shalf[k] = 0.5f * ((s0 + s1) + (s2 + s3));
    }

    int n = blockIdx.x * PPB + lane; // 0..131071
    int b = n >> 12;
    int hw = n & 4095;
    const float* base = qin + ((size_t)b << 18) + hw;

    // x[d] = base[d<<12]; 16 named float4 chunks (dims 4i..4i+3)
#define LOADX(I) make_float4(base[(size_t)(4 * (I) + 0) << 12], \
                             base[(size_t)(4 * (I) + 1) << 12], \
                             base[(size_t)(4 * (I) + 2) << 12], \
                             base[(size_t)(4 * (I) + 3) << 12])
    float4 x0 = LOADX(0),  x1 = LOADX(1),  x2 = LOADX(2),  x3 = LOADX(3);
    float4 x4 = LOADX(4),  x5 = LOADX(5),  x6 = LOADX(6),  x7 = LOADX(7);
    float4 x8 = LOADX(8),  x9 = LOADX(9),  x10 = LOADX(10), x11 = LOADX(11);
    float4 x12 = LOADX(12), x13 = LOADX(13), x14 = LOADX(14), x15 = LOADX(15);
#undef LOADX

    __syncthreads();

    // scan this wave's K-range; k0 forced to SGPR so codebook loads stay scalar
    int k0 = __builtin_amdgcn_readfirstlane(w * KRANGE);
    float bscore = -INFINITY;
    int bidx = k0;
#pragma unroll 2
    for (int kk = 0; kk < KRANGE; ++kk) {
        int k = k0 + kk;
        const float4* c4 = (const float4*)(cb + (size_t)k * DIM);
        float d0 = 0.f, d1 = 0.f, d2 = 0.f, d3 = 0.f;
#define DOT4(X, I)                              \
        {                                       \
            float4 c = c4[I];                   \
            d0 = fmaf((X).x, c.x, d0);          \
            d1 = fmaf((X).y, c.y, d1);          \
            d2 = fmaf((X).z, c.z, d2);          \
            d3 = fmaf((X).w, c.w, d3);          \
        }
        DOT4(x0, 0)  DOT4(x1, 1)  DOT4(x2, 2)  DOT4(x3, 3)
        DOT4(x4, 4)  DOT4(x5, 5)  DOT4(x6, 6)  DOT4(x7, 7)
        DOT4(x8, 8)  DOT4(x9, 9)  DOT4(x10, 10) DOT4(x11, 11)
        DOT4(x12, 12) DOT4(x13, 13) DOT4(x14, 14) DOT4(x15, 15)
#undef DOT4
        float score = ((d0 + d1) + (d2 + d3)) - shalf[k];
        if (score > bscore) { bscore = score; bidx = k; } // strict: first/smallest k wins ties
    }
    sscore[w][lane] = bscore;
    sidx[w][lane] = bidx;
    __syncthreads();

    // combine 4 ranges (wave 0); strict > keeps lower range => smallest k on ties
    if (w == 0) {
        float s = sscore[0][lane];
        int i = sidx[0][lane];
#pragma unroll
        for (int ww = 1; ww < KSPLIT; ++ww) {
            float s2 = sscore[ww][lane];
            int i2 = sidx[ww][lane];
            if (s2 > s) { s = s2; i = i2; }
        }
        sfinal[lane] = i;
        idx_out[n] = (float)i;
    }
    __syncthreads();

    // gather + store + loss: wave w handles dims [w*16, w*16+16) for point=lane.
    int ci = sfinal[lane];
    float lsum;
#define GB4(XA, J)                                                   \
    {                                                                \
        float v0 = crow[(J) + 0], v1 = crow[(J) + 1];                \
        float v2 = crow[(J) + 2], v3 = crow[(J) + 3];                \
        obase[(size_t)((J) + 0) << 12] = v0;                         \
        obase[(size_t)((J) + 1) << 12] = v1;                         \
        obase[(size_t)((J) + 2) << 12] = v2;                         \
        obase[(size_t)((J) + 3) << 12] = v3;                         \
        float e0 = v0 - (XA).x, e1 = v1 - (XA).y;                    \
        float e2 = v2 - (XA).z, e3 = v3 - (XA).w;                    \
        l0 = fmaf(e0, e0, l0); l1 = fmaf(e1, e1, l1);                \
        l2 = fmaf(e2, e2, l2); l3 = fmaf(e3, e3, l3);                \
    }
#define GATHER_BODY(W, XA, XB, XC, XD)                                          \
    {                                                                           \
        const float* crow = cb + ci * DIM + (W)*16;                             \
        float* obase = out + ((size_t)b << 18) + ((size_t)((W)*16) << 12) + hw; \
        float l0 = 0.f, l1 = 0.f, l2 = 0.f, l3 = 0.f;                           \
        GB4(XA, 0) GB4(XB, 4) GB4(XC, 8) GB4(XD, 12)                            \
        lsum = (l0 + l1) + (l2 + l3);                                           \
    }
    if (w == 0) GATHER_BODY(0, x0, x1, x2, x3)
    else if (w == 1) GATHER_BODY(1, x4, x5, x6, x7)
    else if (w == 2) GATHER_BODY(2, x8, x9, x10, x11)
    else GATHER_BODY(3, x12, x13, x14, x15)
#undef GATHER_BODY
#undef GB4

    // wave reduce then one atomic per block
    float s = lsum;
#pragma unroll
    for (int off = 32; off > 0; off >>= 1) s += __shfl_down(s, off);
    if (lane == 0) wsum[w] = s;
    __syncthreads();
    if (tid == 0) atomicAdd(loss_acc, (wsum[0] + wsum[1]) + (wsum[2] + wsum[3]));
}

__global__ void finalize_kernel(float* __restrict__ loss) {
    // loss = (1 + BETA) * mean(diff^2), BETA = 0.2
    loss[0] = 1.2f * loss[0] / 8388608.0f;
}

extern "C" void kernel_launch(void* const* d_in, const int* in_sizes, int n_in,
                              void* d_out, int out_size, void* d_ws, size_t ws_size,
                              hipStream_t stream) {
    const float* qin = (const float*)d_in[0]; // (32,64,64,64) f32
    const float* cb = (const float*)d_in[1];  // (512,64) f32
    float* out = (float*)d_out;               // quant_out: 8388608 floats
    float* loss_out = out + NQ;               // 1 float
    float* idx_out = out + NQ + 1;            // 131072 floats (indices as float)

    init_kernel<<<1, 1, 0, stream>>>(loss_out);
    vq_kernel<<<NPTS / PPB, 256, 0, stream>>>(qin, cb, out, loss_out, idx_out);
    finalize_kernel<<<1, 1, 0, stream>>>(loss_out);
}